// Round 9
// baseline (62.333 us; speedup 1.0000x reference)
//
#include <hip/hip_runtime.h>

// VoxelQueryAndGrouping — MI355X (gfx950), round 9
// = round-5 kernel (PASSED, 53.4us) with exactly ONE delta:
//   candidate-point gathers read padded xyz4 (one dwordx4 each) instead of
//   3 scalar dwords. (Delta validated by r8 Output-0 pass + r3 full pass.)
// grouped_xyz / features / empty paths are byte-identical to round 5.

constexpr int ZG = 21;
constexpr int YG = 400;
constexpr int XG = 352;
constexpr int NS = 16;   // NSAMPLE
constexpr int CF = 32;   // feature channels
constexpr float R2 = 64.0f; // RADIUS^2

typedef float v4f __attribute__((ext_vector_type(4)));

__global__ __launch_bounds__(256) void pad_xyz_kernel(
    const float* __restrict__ xyz, float4* __restrict__ xyz4, int N)
{
    const int i = blockIdx.x * 256 + threadIdx.x;
    if (i < N) {
        const float* p = xyz + (size_t)i * 3;
        xyz4[i] = make_float4(p[0], p[1], p[2], 0.0f);
    }
}

__global__ __launch_bounds__(256) void vqg_kernel(
    const int*    __restrict__ new_coords,     // (M,4) [b,z,y,x]
    const float*  __restrict__ xyz,            // (N,3) original
    const float4* __restrict__ xyz4,           // (N,4) padded
    const int*    __restrict__ xyz_batch_cnt,  // (B,)
    const float*  __restrict__ new_xyz,        // (M,3)
    const float*  __restrict__ features,       // (N,CF)
    const int*    __restrict__ v2p,            // (B,ZG,YG,XG)
    float* __restrict__ out_feat,              // (M,CF,NS)
    float* __restrict__ out_xyz,               // (M,3,NS)
    float* __restrict__ out_empty,             // (M,)
    int M)
{
    const int lane = threadIdx.x & 63;
    const int w    = (blockIdx.x * 256 + threadIdx.x) >> 6;  // wave id
    const int m0   = w * 2;
    const int m1   = m0 + 1;
    if (m0 >= M) return;                      // wave-uniform exit
    const bool has1 = (m1 < M);

    // ---- query descriptors (wave-uniform lines) ----
    const int4 qc0 = *reinterpret_cast<const int4*>(new_coords + (size_t)m0 * 4);
    const int4 qc1 = has1 ? *reinterpret_cast<const int4*>(new_coords + (size_t)m1 * 4) : qc0;
    const float qx0 = new_xyz[m0 * 3 + 0], qy0 = new_xyz[m0 * 3 + 1], qz0 = new_xyz[m0 * 3 + 2];
    const float qx1 = has1 ? new_xyz[m1 * 3 + 0] : 0.f;
    const float qy1 = has1 ? new_xyz[m1 * 3 + 1] : 0.f;
    const float qz1 = has1 ? new_xyz[m1 * 3 + 2] : 0.f;

    int boff0 = 0, boff1 = 0;
    for (int i = 0; i < qc0.x; ++i) boff0 += xyz_batch_cnt[i];
    for (int i = 0; i < qc1.x; ++i) boff1 += xyz_batch_cnt[i];

    // ---- neighbor decode (reference order: dz slowest, dx fastest) ----
    const int n1 = 64 + lane;
    const int dz0 = lane / 25 - 2, dy0 = (lane / 5) % 5 - 2, dx0 = lane % 5 - 2;
    const int dz1 = n1 / 25 - 2,   dy1 = (n1 / 5) % 5 - 2,   dx1 = n1 % 5 - 2;
    const bool in1 = (n1 < 125);

    const int* __restrict__ gb0 = v2p + (size_t)qc0.x * (ZG * YG * XG);
    const int* __restrict__ gb1 = v2p + (size_t)qc1.x * (ZG * YG * XG);

    // ---- all v2p gathers back-to-back ----
    int pa0 = -1, pa1 = -1, pb0 = -1, pb1 = -1;  // p{query}{pass}
    {
        const int z = qc0.y + dz0, y = qc0.z + dy0, x = qc0.w + dx0;
        if ((unsigned)z < (unsigned)ZG && (unsigned)y < (unsigned)YG && (unsigned)x < (unsigned)XG)
            pa0 = gb0[((size_t)z * YG + y) * XG + x];
    }
    {
        const int z = qc0.y + dz1, y = qc0.z + dy1, x = qc0.w + dx1;
        if (in1 && (unsigned)z < (unsigned)ZG && (unsigned)y < (unsigned)YG && (unsigned)x < (unsigned)XG)
            pa1 = gb0[((size_t)z * YG + y) * XG + x];
    }
    if (has1) {
        const int z = qc1.y + dz0, y = qc1.z + dy0, x = qc1.w + dx0;
        if ((unsigned)z < (unsigned)ZG && (unsigned)y < (unsigned)YG && (unsigned)x < (unsigned)XG)
            pb0 = gb1[((size_t)z * YG + y) * XG + x];
    }
    if (has1) {
        const int z = qc1.y + dz1, y = qc1.z + dy1, x = qc1.w + dx1;
        if (in1 && (unsigned)z < (unsigned)ZG && (unsigned)y < (unsigned)YG && (unsigned)x < (unsigned)XG)
            pb1 = gb1[((size_t)z * YG + y) * XG + x];
    }

    // ---- candidate-point gathers: ONE dwordx4 each (the round-9 delta) ----
    float4 A0 = make_float4(0, 0, 0, 0), A1 = A0, B0 = A0, B1 = A0;
    if (pa0 >= 0) A0 = xyz4[pa0];
    if (pa1 >= 0) A1 = xyz4[pa1];
    if (pb0 >= 0) B0 = xyz4[pb0];
    if (pb1 >= 0) B1 = xyz4[pb1];

    // ---- distances (exact reference association, no FMA) ----
    bool va0 = false, va1 = false, vb0 = false, vb1 = false;
    if (pa0 >= 0) {
        const float dx = A0.x - qx0, dy = A0.y - qy0, dz = A0.z - qz0;
        va0 = __fadd_rn(__fadd_rn(__fmul_rn(dx, dx), __fmul_rn(dy, dy)), __fmul_rn(dz, dz)) < R2;
    }
    if (pa1 >= 0) {
        const float dx = A1.x - qx0, dy = A1.y - qy0, dz = A1.z - qz0;
        va1 = __fadd_rn(__fadd_rn(__fmul_rn(dx, dx), __fmul_rn(dy, dy)), __fmul_rn(dz, dz)) < R2;
    }
    if (pb0 >= 0) {
        const float dx = B0.x - qx1, dy = B0.y - qy1, dz = B0.z - qz1;
        vb0 = __fadd_rn(__fadd_rn(__fmul_rn(dx, dx), __fmul_rn(dy, dy)), __fmul_rn(dz, dz)) < R2;
    }
    if (pb1 >= 0) {
        const float dx = B1.x - qx1, dy = B1.y - qy1, dz = B1.z - qz1;
        vb1 = __fadd_rn(__fadd_rn(__fmul_rn(dx, dx), __fmul_rn(dy, dy)), __fmul_rn(dz, dz)) < R2;
    }

    const unsigned long long below = (1ull << lane) - 1ull;
    const int junk = (16 + (lane & 31)) << 2;

    // ---- query 0: ordered slot scatter (r5-proven) ----
    int cnt0, gfin0;
    {
        const unsigned long long bal0 = __ballot(va0);
        const unsigned long long bal1 = __ballot(va1);
        const int c0   = (int)__popcll(bal0);
        cnt0 = c0 + (int)__popcll(bal1);
        const int pos0 = (int)__popcll(bal0 & below);
        const int pos1 = c0 + (int)__popcll(bal1 & below);
        const int addr0 = (va0 && pos0 < NS) ? (pos0 << 2) : junk;
        const int addr1 = (va1 && pos1 < NS) ? (pos1 << 2) : junk;
        const int perm0 = __builtin_amdgcn_ds_permute(addr0, pa0);
        const int perm1 = __builtin_amdgcn_ds_permute(addr1, pa1);
        const int sel   = (lane < c0) ? perm0 : perm1;
        const int first = __shfl(sel, 0);
        const int c16   = cnt0 < NS ? cnt0 : NS;
        gfin0 = (cnt0 == 0) ? boff0 : (((lane & 15) < c16) ? sel : first);
    }
    // ---- query 1 ----
    int cnt1 = 0, gfin1 = 0;
    if (has1) {
        const unsigned long long bal0 = __ballot(vb0);
        const unsigned long long bal1 = __ballot(vb1);
        const int c0   = (int)__popcll(bal0);
        cnt1 = c0 + (int)__popcll(bal1);
        const int pos0 = (int)__popcll(bal0 & below);
        const int pos1 = c0 + (int)__popcll(bal1 & below);
        const int addr0 = (vb0 && pos0 < NS) ? (pos0 << 2) : junk;
        const int addr1 = (vb1 && pos1 < NS) ? (pos1 << 2) : junk;
        const int perm0 = __builtin_amdgcn_ds_permute(addr0, pb0);
        const int perm1 = __builtin_amdgcn_ds_permute(addr1, pb1);
        const int sel   = (lane < c0) ? perm0 : perm1;
        const int first = __shfl(sel, 0);
        const int c16   = cnt1 < NS ? cnt1 : NS;
        gfin1 = (cnt1 == 0) ? boff1 : (((lane & 15) < c16) ? sel : first);
    }

    // ---- grouped_xyz + empty: r5's exact passing pattern ----
    {
        const int s = lane & 15;
        const int d = lane >> 4;
        if (lane < 48) {
            const int row = __shfl(gfin0, s);
            __builtin_nontemporal_store(xyz[(size_t)row * 3 + d],
                                        out_xyz + (size_t)m0 * 48 + d * 16 + s);
        }
        if (lane == 0)
            __builtin_nontemporal_store(cnt0 == 0 ? 1.0f : 0.0f, out_empty + m0);
        if (has1) {
            if (lane < 48) {
                const int row = __shfl(gfin1, s);
                __builtin_nontemporal_store(xyz[(size_t)row * 3 + d],
                                            out_xyz + (size_t)m1 * 48 + d * 16 + s);
            }
            if (lane == 0)
                __builtin_nontemporal_store(cnt1 == 0 ? 1.0f : 0.0f, out_empty + m1);
        }
    }

    // ---- grouped_features: r5's exact passing pattern ----
    const int s0lane = (lane & 3) << 2;
    const int a_r0 = __shfl(gfin0, s0lane + 0);
    const int a_r1 = __shfl(gfin0, s0lane + 1);
    const int a_r2 = __shfl(gfin0, s0lane + 2);
    const int a_r3 = __shfl(gfin0, s0lane + 3);
    const int b_r0 = __shfl(gfin1, s0lane + 0);
    const int b_r1 = __shfl(gfin1, s0lane + 1);
    const int b_r2 = __shfl(gfin1, s0lane + 2);
    const int b_r3 = __shfl(gfin1, s0lane + 3);

    float* __restrict__ of0 = out_feat + (size_t)m0 * (CF * NS);
    float* __restrict__ of1 = out_feat + (size_t)m1 * (CF * NS);
    #pragma unroll
    for (int k = 0; k < 2; ++k) {
        const int c = k * 16 + (lane >> 2);
        v4f v;
        v[0] = features[(size_t)a_r0 * CF + c];
        v[1] = features[(size_t)a_r1 * CF + c];
        v[2] = features[(size_t)a_r2 * CF + c];
        v[3] = features[(size_t)a_r3 * CF + c];
        __builtin_nontemporal_store(v, reinterpret_cast<v4f*>(of0 + k * 256 + (lane << 2)));
    }
    if (has1) {
        #pragma unroll
        for (int k = 0; k < 2; ++k) {
            const int c = k * 16 + (lane >> 2);
            v4f v;
            v[0] = features[(size_t)b_r0 * CF + c];
            v[1] = features[(size_t)b_r1 * CF + c];
            v[2] = features[(size_t)b_r2 * CF + c];
            v[3] = features[(size_t)b_r3 * CF + c];
            __builtin_nontemporal_store(v, reinterpret_cast<v4f*>(of1 + k * 256 + (lane << 2)));
        }
    }
}

extern "C" void kernel_launch(void* const* d_in, const int* in_sizes, int n_in,
                              void* d_out, int out_size, void* d_ws, size_t ws_size,
                              hipStream_t stream) {
    const int*   new_coords    = (const int*)d_in[0];
    const float* xyz           = (const float*)d_in[1];
    const int*   xyz_batch_cnt = (const int*)d_in[2];
    const float* new_xyz       = (const float*)d_in[3];
    // d_in[4] = new_xyz_batch_cnt (unused)
    const float* features      = (const float*)d_in[5];
    const int*   v2p           = (const int*)d_in[6];

    const int M = in_sizes[0] / 4;
    const int N = in_sizes[1] / 3;

    float* out_feat  = (float*)d_out;                       // M*CF*NS
    float* out_xyz   = out_feat + (size_t)M * CF * NS;      // M*3*NS
    float* out_empty = out_xyz + (size_t)M * 3 * NS;        // M

    float4* xyz4 = (float4*)d_ws;
    pad_xyz_kernel<<<(N + 255) / 256, 256, 0, stream>>>(xyz, xyz4, N);

    const int waves  = (M + 1) / 2;           // 2 queries per wave
    const int blocks = (waves + 3) / 4;       // 4 waves per block
    vqg_kernel<<<blocks, 256, 0, stream>>>(
        new_coords, xyz, xyz4, xyz_batch_cnt, new_xyz, features, v2p,
        out_feat, out_xyz, out_empty, M);
}